// Round 5
// baseline (113.218 us; speedup 1.0000x reference)
//
#include <hip/hip_runtime.h>

// SelfAttentionPool, fused kernel v9 (round 10).
// History: v4 28.6us kernel -> v5/v6 compute-shaving (null) -> v7 GPB=2 via
// registers (SPILL, 43.5us) -> v8 GPB=2 via global_load_lds prefetch +
// no-drain barriers (~26.5us, best). v8 residual: the full __syncthreads at
// B-start waits vmcnt(0), and vmcnt counts STORES -> A's 27MB store drain
// (~4.1us grid-wide) serializes before B's compute.
// v9: A's x_new/edge stores DEFERRED: payload snapshotted to registers after
//     A's B6 (v scaled in place, nid + edge float4s captured), stores issued
//     only after B's dot. The single vmcnt(0) before B's dot covers just the
//     xB prefetch (big stores not yet issued -> cheap). B's dot uses temps
//     (not v) so no store-source register reuse hazard; B's x_new phase
//     re-reads xB from LDS (~0.4us aggregate). A's store drain now overlaps
//     B's compute phases.
// Numerics: z pipeline stays f64 (selection matches JAX f32 ranking).
//
// Output (float32): x_new (80000*128) | edge0 (E) | edge1 (E) | batch_new (80000)

#define NPG   100
#define EPG   1600
#define KNUM  80
#define FDIM  128
#define BT    512
#define NF4   (NPG * FDIM / 4)   // 3200 float4 of x per graph
#define NE4   (EPG / 4)          // 400 int4 per edge row
#define NCH   (NF4 / BT)         // 6 full chunks
#define NREM  (NF4 - NCH * BT)   // 128 remainder float4
#define P8    9                  // padded partial row stride (doubles)

struct Smem {
    alignas(16) float xB[NPG * FDIM];   // 51200B: staged x for graph B
    int4   edge4[NE4];                  // 6400B  packed: s | (d<<16)
    int    cnt[8][NPG];                 // 3200B  per-wave private degree
    double part[NPG * P8];              // 7200B  dot partials (8/node)
    double dis[NPG];                    // 800B
    double a[NPG];                      // 800B   s * dis
    double zp[8][NPG];                  // 6400B  per-wave private scatter
    double z[NPG];                      // 800B
    unsigned long long mask7[8];        // 64B
    int    newid[NPG];                  // 400B
    float  scalen[NPG];                 // 400B
};                                      // ~77.7KB -> 2 blocks/CU

typedef __attribute__((address_space(1))) const unsigned int gu32;
typedef __attribute__((address_space(3))) unsigned int lu32;

// Barrier WITHOUT vmcnt drain: LDS producer/consumer ordering only.
__device__ __forceinline__ void bar_nodrain() {
    asm volatile("s_waitcnt lgkmcnt(0)" ::: "memory");
    __builtin_amdgcn_s_barrier();
    asm volatile("" ::: "memory");
}

// init -> edge pack -> (dot done by caller) assumed; this runs the shared
// middle: reduce -> scatter -> z -> rank -> lead. Caller must have passed
// the B2 barrier; ends after the B6 barrier (newid/scalen valid).
__device__ __forceinline__
void mid_phases(Smem& sm, int g, int tid, int wave, int lane,
                float* __restrict__ out, int E_total, int out_x_elems)
{
    int* sh_edge = (int*)sm.edge4;

    // ---- reduce: 1 thread/node sums 8 partials; folds deg -> dis, a
    if (tid < NPG) {
        const double* pr = sm.part + tid * P8;
        double s = ((pr[0] + pr[1]) + (pr[2] + pr[3]))
                 + ((pr[4] + pr[5]) + (pr[6] + pr[7]));
        int deg = 1 + sm.cnt[0][tid] + sm.cnt[1][tid] + sm.cnt[2][tid]
                    + sm.cnt[3][tid] + sm.cnt[4][tid] + sm.cnt[5][tid]
                    + sm.cnt[6][tid] + sm.cnt[7][tid];
        double dis = 1.0 / sqrt((double)deg);
        sm.dis[tid] = dis;
        sm.a[tid]   = s * dis;
    }
    bar_nodrain();                                // B3: dis/a ready

    // ---- z scatter: accumulate sum of a[s] per dst (dis[d] hoisted)
    {
        double* zw = sm.zp[wave];
        for (int j = tid; j < EPG; j += BT) {
            int e = sh_edge[j];
            atomicAdd(&zw[e >> 16], sm.a[e & 0xffff]);
        }
    }
    bar_nodrain();                                // B4: scatter done

    if (tid < NPG) {
        double zi = sm.a[tid]                     // self-loop term
                  + sm.zp[0][tid] + sm.zp[1][tid] + sm.zp[2][tid] + sm.zp[3][tid]
                  + sm.zp[4][tid] + sm.zp[5][tid] + sm.zp[6][tid] + sm.zp[7][tid];
        sm.z[tid] = zi * sm.dis[tid];
        sm.newid[tid] = -1;
    }
    bar_nodrain();                                // B5: z ready

    // ---- top-k rank, 4 threads/node (25 scans each) + shfl combine
    const bool rk = tid < 4 * NPG;
    const int  n2 = tid >> 2;
    int r = 0;
    double zn = 0.0;
    if (rk) {
        zn = sm.z[n2];
        const int j0 = (tid & 3) * 25;
        for (int j = j0; j < j0 + 25; ++j) {
            double zj = sm.z[j];
            r += (int)((zj > zn) | ((zj == zn) & (j < n2)));
        }
    }
    r += __shfl_xor(r, 1, 64);
    r += __shfl_xor(r, 2, 64);
    const bool lead = rk && ((tid & 3) == 0) && (r < KNUM);
    unsigned long long m = __ballot(lead);
    if (lane == 0) sm.mask7[wave] = m;
    bar_nodrain();                                // B6a: masks ready

    if (lead) {
        int before = __popcll(m & ((1ull << lane) - 1ull));
        for (int w2 = 0; w2 < wave; ++w2) before += __popcll(sm.mask7[w2]);
        int row = g * KNUM + before;
        sm.newid[n2]  = row;
        sm.scalen[n2] = 1.0f / (1.0f + __expf(-(float)zn));
        out[(size_t)out_x_elems + 2 * (size_t)E_total + row] = (float)g;
    }
    bar_nodrain();                                // B6: newid/scalen ready
}

// pack edges into sm.edge4 + per-wave degree histogram; returns packed reg
__device__ __forceinline__
int4 pack_edges(Smem& sm, int base, int tid, int wave, int4 es, int4 ed)
{
    int4 s4 = es, d4 = ed;
    s4.x -= base; s4.y -= base; s4.z -= base; s4.w -= base;
    d4.x -= base; d4.y -= base; d4.z -= base; d4.w -= base;
    int4 p; p.x = s4.x | (d4.x << 16); p.y = s4.y | (d4.y << 16);
            p.z = s4.z | (d4.z << 16); p.w = s4.w | (d4.w << 16);
    sm.edge4[tid] = p;
    int* cw = sm.cnt[wave];
    atomicAdd(&cw[s4.x], 1); atomicAdd(&cw[s4.y], 1);
    atomicAdd(&cw[s4.z], 1); atomicAdd(&cw[s4.w], 1);
    return p;
}

__device__ __forceinline__
float4 edge_payload(Smem& sm, int4 p, bool lo)    // lo: e0 (src) else e1 (dst)
{
    float4 o;
    {
        int a_ = sm.newid[p.x & 0xffff], b_ = sm.newid[p.x >> 16];
        bool vv = (a_ >= 0) && (b_ >= 0);
        o.x = vv ? (float)(lo ? a_ : b_) : -1.0f;
    }
    {
        int a_ = sm.newid[p.y & 0xffff], b_ = sm.newid[p.y >> 16];
        bool vv = (a_ >= 0) && (b_ >= 0);
        o.y = vv ? (float)(lo ? a_ : b_) : -1.0f;
    }
    {
        int a_ = sm.newid[p.z & 0xffff], b_ = sm.newid[p.z >> 16];
        bool vv = (a_ >= 0) && (b_ >= 0);
        o.z = vv ? (float)(lo ? a_ : b_) : -1.0f;
    }
    {
        int a_ = sm.newid[p.w & 0xffff], b_ = sm.newid[p.w >> 16];
        bool vv = (a_ >= 0) && (b_ >= 0);
        o.w = vv ? (float)(lo ? a_ : b_) : -1.0f;
    }
    return o;
}

__global__ __launch_bounds__(BT, 4)
void sagpool_fused9(const float* __restrict__ x,
                    const int*   __restrict__ ei,
                    const float* __restrict__ theta,
                    float* __restrict__ out,
                    int E_total, int out_x_elems, int n_graphs)
{
    __shared__ Smem sm;
    const int tid  = threadIdx.x;
    const int wave = tid >> 6;
    const int lane = tid & 63;
    const int gA   = blockIdx.x * 2;
    const int gB   = gA + 1;
    const bool hasE = tid < NE4;
    const bool hasR = tid < NREM;
    const bool doB  = gB < n_graphs;

    const float4 th = ((const float4*)theta)[lane & 31];
    float4* outx = (float4*)out;
    float* e0 = out + out_x_elems;
    float* e1 = e0 + E_total;

    // ---- t0 loads: A+B edges, A x-tile into registers
    int4 esA = {0,0,0,0}, edA = {0,0,0,0}, esB = {0,0,0,0}, edB = {0,0,0,0};
    if (hasE) {
        esA = ((const int4*)(ei + (size_t)gA * EPG))[tid];
        edA = ((const int4*)(ei + (size_t)E_total + (size_t)gA * EPG))[tid];
        if (doB) {
            esB = ((const int4*)(ei + (size_t)gB * EPG))[tid];
            edB = ((const int4*)(ei + (size_t)E_total + (size_t)gB * EPG))[tid];
        }
    }
    float4 v[NCH];
    float4 vR = {0.f, 0.f, 0.f, 0.f};
    const float4* xA = (const float4*)(x + (size_t)gA * NPG * FDIM);
    const float4* xB = (const float4*)(x + (size_t)gB * NPG * FDIM);
    #pragma unroll
    for (int i = 0; i < NCH; ++i) v[i] = xA[i * BT + tid];
    if (hasR) vR = xA[NCH * BT + tid];

    // ================= graph A =================
    {
        int*    cw = sm.cnt[wave];
        double* zw = sm.zp[wave];
        for (int i = lane; i < NPG; i += 64) { cw[i] = 0; zw[i] = 0.0; }
    }
    int4 pA = {0,0,0,0};
    if (hasE) pA = pack_edges(sm, gA * NPG, tid, wave, esA, edA);

    // dot A from registers; 2 shfl folds -> 8 partials/node
    #pragma unroll
    for (int i = 0; i < NCH; ++i) {
        int idx = i * BT + tid;
        double dp = (double)v[i].x * th.x + (double)v[i].y * th.y
                  + (double)v[i].z * th.z + (double)v[i].w * th.w;
        dp += __shfl_xor(dp, 1, 64);
        dp += __shfl_xor(dp, 2, 64);
        if ((lane & 3) == 0)
            sm.part[(idx >> 5) * P8 + ((idx & 31) >> 2)] = dp;
    }
    if (hasR) {
        int idx = NCH * BT + tid;
        double dp = (double)vR.x * th.x + (double)vR.y * th.y
                  + (double)vR.z * th.z + (double)vR.w * th.w;
        dp += __shfl_xor(dp, 1, 64);
        dp += __shfl_xor(dp, 2, 64);
        if ((lane & 3) == 0)
            sm.part[(idx >> 5) * P8 + ((idx & 31) >> 2)] = dp;
    }

    // async-stage graph B's x into LDS (A's x already consumed; these queue
    // behind the grid's first load wave -> stagger). Zero VGPR cost.
    if (doB) {
        #pragma unroll
        for (int i = 0; i < NCH; ++i) {
            int idx = i * BT + tid;
            __builtin_amdgcn_global_load_lds((gu32*)(xB + idx),
                (lu32*)(sm.xB + (size_t)(i * BT + wave * 64) * 4), 16, 0, 0);
        }
        if (wave < 2) {
            int idx = NCH * BT + tid;
            __builtin_amdgcn_global_load_lds((gu32*)(xB + idx),
                (lu32*)(sm.xB + (size_t)(NCH * BT + wave * 64) * 4), 16, 0, 0);
        }
    }
    bar_nodrain();                                // B2: edges, cnt, partials

    mid_phases(sm, gA, tid, wave, lane, out, E_total, out_x_elems);

    // ---- snapshot A's store payload into registers (reads only)
    int nidA[NCH], nidAR = -1;
    #pragma unroll
    for (int i = 0; i < NCH; ++i) {
        int row = (i * BT + tid) >> 5;
        int nid = sm.newid[row];
        nidA[i] = nid;
        if (nid >= 0) {
            float sc = sm.scalen[row];
            v[i].x *= sc; v[i].y *= sc; v[i].z *= sc; v[i].w *= sc;
        }
    }
    if (hasR) {
        int row = (NCH * BT + tid) >> 5;
        nidAR = sm.newid[row];
        if (nidAR >= 0) {
            float sc = sm.scalen[row];
            vR.x *= sc; vR.y *= sc; vR.z *= sc; vR.w *= sc;
        }
    }
    float4 o0A = {0,0,0,0}, o1A = {0,0,0,0};
    if (hasE) {
        o0A = edge_payload(sm, pA, true);
        o1A = edge_payload(sm, pA, false);
    }
    bar_nodrain();                   // B7: all A-reads of LDS complete

    if (!doB) {                      // tail safety (not hit at B=1000 even)
        #pragma unroll
        for (int i = 0; i < NCH; ++i) {
            int idx = i * BT + tid;
            if (nidA[i] >= 0) outx[(size_t)nidA[i] * 32 + (idx & 31)] = v[i];
        }
        if (hasR && nidAR >= 0)
            outx[(size_t)nidAR * 32 + ((NCH * BT + tid) & 31)] = vR;
        if (hasE) {
            ((float4*)e0)[(size_t)gA * NE4 + tid] = o0A;
            ((float4*)e1)[(size_t)gA * NE4 + tid] = o1A;
        }
        return;
    }

    // ================= graph B =================
    {
        int*    cw = sm.cnt[wave];
        double* zw = sm.zp[wave];
        for (int i = lane; i < NPG; i += 64) { cw[i] = 0; zw[i] = 0.0; }
    }
    int4 pB = {0,0,0,0};
    if (hasE) pB = pack_edges(sm, gB * NPG, tid, wave, esB, edB);

    // xB landed? Only the prefetch (+1 batch dword) is outstanding in vmcnt
    // here -- A's big stores are NOT yet issued, so this wait is cheap.
    asm volatile("s_waitcnt vmcnt(0)" ::: "memory");

    // dot B from LDS into short-lived temps (leaves v = A's payload intact)
    const float4* xl = (const float4*)sm.xB;
    #pragma unroll
    for (int i = 0; i < NCH; ++i) {
        int idx = i * BT + tid;
        float4 w4 = xl[idx];
        double dp = (double)w4.x * th.x + (double)w4.y * th.y
                  + (double)w4.z * th.z + (double)w4.w * th.w;
        dp += __shfl_xor(dp, 1, 64);
        dp += __shfl_xor(dp, 2, 64);
        if ((lane & 3) == 0)
            sm.part[(idx >> 5) * P8 + ((idx & 31) >> 2)] = dp;
    }
    if (hasR) {
        int idx = NCH * BT + tid;
        float4 w4 = xl[idx];
        double dp = (double)w4.x * th.x + (double)w4.y * th.y
                  + (double)w4.z * th.z + (double)w4.w * th.w;
        dp += __shfl_xor(dp, 1, 64);
        dp += __shfl_xor(dp, 2, 64);
        if ((lane & 3) == 0)
            sm.part[(idx >> 5) * P8 + ((idx & 31) >> 2)] = dp;
    }

    // ---- issue A's deferred stores (registers only); they drain under
    // B's scatter/rank phases instead of serializing at a barrier.
    #pragma unroll
    for (int i = 0; i < NCH; ++i) {
        int idx = i * BT + tid;
        if (nidA[i] >= 0) outx[(size_t)nidA[i] * 32 + (idx & 31)] = v[i];
    }
    if (hasR && nidAR >= 0)
        outx[(size_t)nidAR * 32 + ((NCH * BT + tid) & 31)] = vR;
    if (hasE) {
        ((float4*)e0)[(size_t)gA * NE4 + tid] = o0A;
        ((float4*)e1)[(size_t)gA * NE4 + tid] = o1A;
    }
    bar_nodrain();                                // B2': B partials ready

    mid_phases(sm, gB, tid, wave, lane, out, E_total, out_x_elems);

    // ---- B stores: re-read xB from LDS, scale, store
    #pragma unroll
    for (int i = 0; i < NCH; ++i) {
        int idx = i * BT + tid;
        int row = idx >> 5;
        int nid = sm.newid[row];
        if (nid >= 0) {
            float sc = sm.scalen[row];
            float4 w4 = xl[idx];
            float4 o;
            o.x = w4.x * sc; o.y = w4.y * sc;
            o.z = w4.z * sc; o.w = w4.w * sc;
            outx[(size_t)nid * 32 + (idx & 31)] = o;
        }
    }
    if (hasR) {
        int idx = NCH * BT + tid;
        int row = idx >> 5;
        int nid = sm.newid[row];
        if (nid >= 0) {
            float sc = sm.scalen[row];
            float4 w4 = xl[idx];
            float4 o;
            o.x = w4.x * sc; o.y = w4.y * sc;
            o.z = w4.z * sc; o.w = w4.w * sc;
            outx[(size_t)nid * 32 + (idx & 31)] = o;
        }
    }
    if (hasE) {
        float4 o0B = edge_payload(sm, pB, true);
        float4 o1B = edge_payload(sm, pB, false);
        ((float4*)e0)[(size_t)gB * NE4 + tid] = o0B;
        ((float4*)e1)[(size_t)gB * NE4 + tid] = o1B;
    }
}

extern "C" void kernel_launch(void* const* d_in, const int* in_sizes, int n_in,
                              void* d_out, int out_size, void* d_ws, size_t ws_size,
                              hipStream_t stream)
{
    const float* x     = (const float*)d_in[0];
    const int*   ei    = (const int*)d_in[1];
    const float* theta = (const float*)d_in[3];
    float* out = (float*)d_out;

    const int N = in_sizes[0] / FDIM;        // 100000
    const int E = in_sizes[1] / 2;           // 1600000
    const int B = N / NPG;                   // 1000
    const int out_x_elems = B * KNUM * FDIM; // 10,240,000
    const int nb = (B + 1) / 2;              // 500 blocks

    sagpool_fused9<<<dim3(nb), dim3(BT), 0, stream>>>(x, ei, theta, out,
                                                      E, out_x_elems, B);
}